// Round 16
// baseline (132.485 us; speedup 1.0000x reference)
//
#include <hip/hip_runtime.h>
#include <hip/hip_bf16.h>
#include <stdint.h>

#define B_DIM 8
#define S_LEN 2048
#define DMODEL 2048
#define HDIM 128

typedef __attribute__((ext_vector_type(4))) float f32x4;
typedef __attribute__((ext_vector_type(8))) short bf16x8;
typedef __attribute__((ext_vector_type(4))) short bf16x4;
typedef __attribute__((ext_vector_type(4))) unsigned int u32x4;
typedef unsigned short u16;
typedef unsigned int u32;

__device__ __forceinline__ u16 f2bf(float f) {
    union { float f; u32 u; } v; v.f = f;
    u32 u = v.u;
    u32 r = (u + 0x7fffu + ((u >> 16) & 1u)) >> 16;
    return (u16)r;
}

__device__ __forceinline__ u32 pk2bf(float a, float b) {
    float2 f2; f2.x = a; f2.y = b;
    __hip_bfloat162 h = __float22bfloat162_rn(f2);
    union { __hip_bfloat162 h; u32 u; } cv; cv.h = h;
    return cv.u;
}

__device__ __forceinline__ void async_copy16(u16* lds, const u16* g) {
    __builtin_amdgcn_global_load_lds((const __attribute__((address_space(1))) u32*)g,
                                     (__attribute__((address_space(3))) u32*)lds,
                                     16, 0, 0);
}

// ---------------- pack weights: transpose [2048 k][128 h] fp32 x3 -> bf16 Wp[384 h][2048 k]
__global__ void pack_weights(const float* __restrict__ Wq, const float* __restrict__ Wk,
                             const float* __restrict__ Wv, u16* __restrict__ Wp) {
    __shared__ u16 tl[64 * 64];
    int t = threadIdx.x;
    int bx = blockIdx.x;                 // 3 w * 32 kt * 2 ht = 192
    int w = bx >> 6;
    int kt = (bx >> 1) & 31;
    int ht = bx & 1;
    int k0 = kt * 64, h0 = ht * 64;
    const float* W = (w == 0) ? Wq : ((w == 1) ? Wk : Wv);

    int kl = t >> 2, hc = t & 3;
    const float* src = W + (size_t)(k0 + kl) * HDIM + h0 + hc * 16;
#pragma unroll
    for (int half = 0; half < 2; half++) {
        bf16x8 p;
#pragma unroll
        for (int j = 0; j < 8; j++) p[j] = (short)f2bf(src[half * 8 + j]);
        int slot = hc * 2 + half;
        *(bf16x8*)((char*)tl + kl * 128 + ((slot ^ (kl & 7)) << 4)) = p;
    }
    __syncthreads();
    int hl = t >> 2, kc = t & 3;
    u16* dst = Wp + (size_t)(w * HDIM + h0 + hl) * DMODEL + k0 + kc * 16;
#pragma unroll
    for (int half = 0; half < 2; half++) {
        bf16x8 p;
#pragma unroll
        for (int j = 0; j < 8; j++) {
            int k = kc * 16 + half * 8 + j;
            p[j] = *(u16*)((char*)tl + k * 128 + (((hl >> 3) ^ (k & 7)) << 4) + (hl & 7) * 2);
        }
        *(bf16x8*)(dst + half * 8) = p;
    }
}

// ---------------- fused QKV projection GEMM: [16384,2048] @ [2048,384] (bf16 MFMA)
// Round-14 kernel (best total): r11 structure + per-block k-ring offset (L2 hotspot
// de-phasing; +3.6us total). BM=64, BN=384, BK=64, grid 256, 8 waves. vmcnt(2) keeps
// the 2 A-prefetch loads in flight across the barrier. V written transposed.
// Ledger: BK=32 bank-conflicts (r8); LDS-free 2x slower (r9); BN=192/2blk-CU null
// (r10); ring-3/4 deeper prefetch null-to-worse (r12/r13). FROZEN.
__launch_bounds__(512)
__global__ void qkv_gemm(const float* __restrict__ hs, const u16* __restrict__ Wp,
                         const float* __restrict__ bq, const float* __restrict__ bk,
                         const float* __restrict__ bv,
                         u16* __restrict__ Qb, u16* __restrict__ Kb, u16* __restrict__ Vt) {
    __shared__ u16 As[2][64 * 64];       // 2 x 8 KB, 16B-slot XOR swizzle
    __shared__ u16 Bs[2][384 * 64];      // 2 x 48 KB, swizzled

    int t = threadIdx.x;
    int wv = t >> 6, l = t & 63, lr = l & 15, lq = l >> 4;
    int wm = wv >> 2, wn = wv & 3;
    int m0 = blockIdx.x * 64;
    int ko = ((blockIdx.x >> 3) & 31) << 6;   // k-ring start: unique per block within an XCD

#define KW(X) (((X) + ko) & (DMODEL - 1))

    f32x4 acc[2][6] = {};

    int ar = t >> 3, aq = t & 7;         // A staging: row 0..63, 8-float chunk 0..7
    const float* gA = hs + (size_t)(m0 + ar) * DMODEL + aq * 8;

    f32x4 p0A, p1A, p0B, p1B;            // two A-prefetch register sets (depth 2)

#define STAGE_B(K0, BUF)                                                    \
    {                                                                       \
        _Pragma("unroll")                                                   \
        for (int i = 0; i < 6; i++) {                                       \
            int c = i * 512 + t;                                            \
            int n = c >> 3, s = c & 7;                                      \
            async_copy16(&Bs[BUF][c * 8],                                   \
                         Wp + (size_t)n * DMODEL + (K0) + ((s ^ (n & 7)) * 8)); \
        }                                                                   \
    }
#define WRITE_A(BUF, V0, V1)                                                \
    {                                                                       \
        u32x4 pk;                                                           \
        pk.x = pk2bf(V0[0], V0[1]); pk.y = pk2bf(V0[2], V0[3]);             \
        pk.z = pk2bf(V1[0], V1[1]); pk.w = pk2bf(V1[2], V1[3]);             \
        *(u32x4*)((char*)&As[BUF][0] + ar * 128 + ((aq ^ (ar & 7)) << 4)) = pk; \
    }
#define COMPUTE(CUR)                                                        \
    {                                                                       \
        _Pragma("unroll")                                                   \
        for (int kk = 0; kk < 2; kk++) {                                    \
            bf16x8 afr[2], bfr[6];                                          \
            int slot = kk * 4 + lq;                                         \
            _Pragma("unroll")                                               \
            for (int mi = 0; mi < 2; mi++) {                                \
                int row = wm * 32 + mi * 16 + lr;                           \
                afr[mi] = *(bf16x8*)((char*)&As[CUR][0] + row * 128 + ((slot ^ (row & 7)) << 4)); \
            }                                                               \
            _Pragma("unroll")                                               \
            for (int ni = 0; ni < 6; ni++) {                                \
                int row = wn * 96 + ni * 16 + lr;                           \
                bfr[ni] = *(bf16x8*)((char*)&Bs[CUR][0] + row * 128 + ((slot ^ (row & 7)) << 4)); \
            }                                                               \
            __builtin_amdgcn_s_setprio(1);                                  \
            _Pragma("unroll")                                               \
            for (int mi = 0; mi < 2; mi++)                                  \
                _Pragma("unroll")                                           \
                for (int ni = 0; ni < 6; ni++)                              \
                    acc[mi][ni] = __builtin_amdgcn_mfma_f32_16x16x32_bf16(afr[mi], bfr[ni], acc[mi][ni], 0, 0, 0); \
            __builtin_amdgcn_s_setprio(0);                                  \
        }                                                                   \
    }
#define SYNC_PIPE                                                           \
    asm volatile("s_waitcnt vmcnt(2) lgkmcnt(0)" ::: "memory");             \
    __builtin_amdgcn_sched_barrier(0);                                      \
    __builtin_amdgcn_s_barrier();                                           \
    __builtin_amdgcn_sched_barrier(0);

    // prologue: tile ko into buf0; prefetch A(ko+64)
    p0A = *(const f32x4*)(gA + KW(0)); p1A = *(const f32x4*)(gA + KW(0) + 4);
    STAGE_B(KW(0), 0);
    WRITE_A(0, p0A, p1A);
    p0A = *(const f32x4*)(gA + KW(64)); p1A = *(const f32x4*)(gA + KW(64) + 4);
    __syncthreads();                     // full drain once (prologue only)

    for (int k0 = 0; k0 < DMODEL; k0 += 128) {
        // even step: compute buf0; stage tile(i+1)->buf1; prefetch A(i+2)
        {
            int ks = KW(k0 + 64);
            int kp = KW(k0 + 128);
            STAGE_B(ks, 1);
            p0B = *(const f32x4*)(gA + kp); p1B = *(const f32x4*)(gA + kp + 4);
            COMPUTE(0);
            WRITE_A(1, p0A, p1A);
            SYNC_PIPE
        }
        // odd step: compute buf1; stage->buf0; prefetch
        {
            int ks = KW(k0 + 128);
            int kp = KW(k0 + 192);
            STAGE_B(ks, 0);
            p0A = *(const f32x4*)(gA + kp); p1A = *(const f32x4*)(gA + kp + 4);
            COMPUTE(1);
            WRITE_A(0, p0B, p1B);
            SYNC_PIPE
        }
    }

    // epilogue: bias; Q pre-scaled by 1/sqrt(128); V written transposed to Vt[b][h][s]
#pragma unroll
    for (int ni = 0; ni < 6; ni++) {
        int col = wn * 96 + ni * 16 + lr;
        int w = col >> 7, h = col & 127;
        const float* bp = (w == 0) ? bq : ((w == 1) ? bk : bv);
        float bias = bp[h];
#pragma unroll
        for (int mi = 0; mi < 2; mi++) {
            int row0 = m0 + wm * 32 + mi * 16 + lq * 4;
            if (w == 2) {
                int b = row0 >> 11, s0 = row0 & (S_LEN - 1);
                bf16x4 pv;
#pragma unroll
                for (int r = 0; r < 4; r++) pv[r] = (short)f2bf(acc[mi][ni][r] + bias);
                *(bf16x4*)(Vt + (size_t)(b * HDIM + h) * S_LEN + s0) = pv;
            } else {
                float scale = (w == 0) ? 0.08838834764831845f : 1.0f;
                u16* dst = (w == 0) ? Qb : Kb;
#pragma unroll
                for (int r = 0; r < 4; r++)
                    dst[(size_t)(row0 + r) * HDIM + h] = f2bf((acc[mi][ni][r] + bias) * scale);
            }
        }
    }
#undef STAGE_B
#undef WRITE_A
#undef COMPUTE
#undef SYNC_PIPE
#undef KW
}

// ---------------- causal flash attention: 4 waves per block split the KV range of ONE
// 16-row Q tile (kt = wv, wv+4, ...); no barriers in main loop; LDS merge at the end.
// launch_bounds(256,4): the LEAN kernel (no pexp array, shuffle-free softmax, per-n PV
// loads) reports VGPR_Count=72 at (256,3) -> fits the 128-reg cap of 4 waves/EU now.
// (r4-6 spills were the FAT kernel.) Tripwire: if WRITE_SIZE >> 8.2MB it spilled ->
// revert to (256,3). LDS 33KB x 4 blocks = 133KB <= 160 OK.
// Defer-max (T13, THR=8) + shuffle-free common path (r15).
__launch_bounds__(256, 4)
__global__ void attn(const u16* __restrict__ Qb, const u16* __restrict__ Kb,
                     const u16* __restrict__ Vt, float* __restrict__ out) {
    __shared__ char lds[33280];          // Om[4][16][128] f32 (32768) + ml[4][16][2] f32 (512)
    float* Om = (float*)lds;
    float* ml = (float*)(lds + 32768);

    int t = threadIdx.x;
    int wv = t >> 6, l = t & 63, lr = l & 15, lq = l >> 4;
    int bx = blockIdx.x;                 // 1024 = 8 b x 128 qt
    int b = bx & 7;                      // batch == XCD for KV L2 locality
    int qt = 127 - (bx >> 3);            // descending work order
    int qr0 = qt * 16;
    size_t qbase = (size_t)b * S_LEN;
    char* Pw = lds + wv * 8192;          // P tile aliases this wave's own Om region

    bf16x8 aqf[4];
#pragma unroll
    for (int kk = 0; kk < 4; kk++)
        aqf[kk] = *(const bf16x8*)(Qb + (qbase + qr0 + lr) * HDIM + kk * 32 + lq * 8);

    f32x4 o_acc[8] = {};
    float m_run[4], l_run[4];
#pragma unroll
    for (int r = 0; r < 4; r++) { m_run[r] = -1e38f; l_run[r] = 0.f; }

    int ktd = qt >> 2;                   // diagonal 64-wide tile index
    const u16* Kbase = Kb + qbase * HDIM;
    const u16* Vbase = Vt + (size_t)b * HDIM * S_LEN;

    for (int kt = wv; kt <= ktd; kt += 4) {
        int kv0 = kt * 64;

        // S = Q K^T : K fragments straight from global (L2-hit)
        f32x4 sa[4] = {};
#pragma unroll
        for (int kk = 0; kk < 4; kk++) {
            bf16x8 bk8[4];
#pragma unroll
            for (int n = 0; n < 4; n++)
                bk8[n] = *(const bf16x8*)(Kbase + (size_t)(kv0 + n * 16 + lr) * HDIM + kk * 32 + lq * 8);
            __builtin_amdgcn_s_setprio(1);
#pragma unroll
            for (int n = 0; n < 4; n++)
                sa[n] = __builtin_amdgcn_mfma_f32_16x16x32_bf16(aqf[kk], bk8[n], sa[n], 0, 0, 0);
            __builtin_amdgcn_s_setprio(0);
        }

        if (kt == ktd) {                 // causal mask on the diagonal tile
#pragma unroll
            for (int n = 0; n < 4; n++) {
                int col = kv0 + n * 16 + lr;
#pragma unroll
                for (int r = 0; r < 4; r++) {
                    int row = qr0 + lq * 4 + r;
                    if (col > row) sa[n][r] = -1e30f;
                }
            }
        }

        // shuffle-free online softmax (16-lane groups own 4 q-rows each)
#pragma unroll
        for (int r = 0; r < 4; r++) {
            float pmx = fmaxf(fmaxf(sa[0][r], sa[1][r]), fmaxf(sa[2][r], sa[3][r]));
            if (__any(pmx > m_run[r] + 8.0f)) {      // rare, wave-uniform
                float mx = pmx;
#pragma unroll
                for (int off = 8; off >= 1; off >>= 1) mx = fmaxf(mx, __shfl_xor(mx, off, 64));
                float mnew = fmaxf(m_run[r], mx);
                float f = __expf(m_run[r] - mnew);
                l_run[r] *= f;                       // per-lane partial scales linearly
                m_run[r] = mnew;
#pragma unroll
                for (int n = 0; n < 8; n++) o_acc[n][r] *= f;
            }
            int prow = lq * 4 + r;
            char* pb = Pw + prow * 128;
#pragma unroll
            for (int n = 0; n < 4; n++) {
                float e = __expf(sa[n][r] - m_run[r]);
                l_run[r] += e;                       // per-lane partial, no shuffles
                int col = n * 16 + lr;
                *(u16*)(pb + (((col >> 3) ^ (prow & 7)) << 4) + (col & 7) * 2) = f2bf(e);
            }
        }

        // O += P V : V fragments straight from global (L2-hit), per-n load+MFMA
        // (per-n form, NOT batched vb8[8]: that spilled in round 4)
#pragma unroll
        for (int kk = 0; kk < 2; kk++) {
            int slot = kk * 4 + lq;
            bf16x8 pa = *(bf16x8*)(Pw + lr * 128 + ((slot ^ (lr & 7)) << 4));
            __builtin_amdgcn_s_setprio(1);
#pragma unroll
            for (int n = 0; n < 8; n++) {
                bf16x8 vb8 = *(const bf16x8*)(Vbase + (size_t)(n * 16 + lr) * S_LEN + kv0 + kk * 32 + lq * 8);
                o_acc[n] = __builtin_amdgcn_mfma_f32_16x16x32_bf16(pa, vb8, o_acc[n], 0, 0, 0);
            }
            __builtin_amdgcn_s_setprio(0);
        }
    }

    // fold the per-lane l partials into group sums (once, not per tile)
#pragma unroll
    for (int r = 0; r < 4; r++) {
#pragma unroll
        for (int off = 8; off >= 1; off >>= 1) l_run[r] += __shfl_xor(l_run[r], off, 64);
    }

    // write partials (Om[wv] overwrites this wave's P area only after its last P read)
    __builtin_amdgcn_sched_barrier(0);
#pragma unroll
    for (int n = 0; n < 8; n++)
#pragma unroll
        for (int r = 0; r < 4; r++)
            Om[wv * 2048 + (lq * 4 + r) * 128 + n * 16 + lr] = o_acc[n][r];
    if (lr == 0) {
#pragma unroll
        for (int r = 0; r < 4; r++) {
            ml[wv * 32 + (lq * 4 + r) * 2 + 0] = m_run[r];
            ml[wv * 32 + (lq * 4 + r) * 2 + 1] = l_run[r];
        }
    }
    __syncthreads();

    // merge the 4 partials: thread -> (row = t>>4, cols (t&15)*8 .. +8)
    {
        int row = t >> 4, c0 = (t & 15) * 8;
        float m4[4], l4[4];
#pragma unroll
        for (int w = 0; w < 4; w++) {
            m4[w] = ml[w * 32 + row * 2 + 0];
            l4[w] = ml[w * 32 + row * 2 + 1];
        }
        float ms = fmaxf(fmaxf(m4[0], m4[1]), fmaxf(m4[2], m4[3]));
        float wt[4], ls = 0.f;
#pragma unroll
        for (int w = 0; w < 4; w++) { wt[w] = __expf(m4[w] - ms); ls += l4[w] * wt[w]; }
        float inv = 1.0f / ls;
        f32x4 r0 = (f32x4)0.f, r1 = (f32x4)0.f;
#pragma unroll
        for (int w = 0; w < 4; w++) {
            const f32x4* Op = (const f32x4*)(Om + w * 2048 + row * 128 + c0);
            r0 += Op[0] * wt[w];
            r1 += Op[1] * wt[w];
        }
        f32x4* dst = (f32x4*)(out + (qbase + qr0 + row) * HDIM + c0);
        dst[0] = r0 * inv;
        dst[1] = r1 * inv;
    }
}

extern "C" void kernel_launch(void* const* d_in, const int* in_sizes, int n_in,
                              void* d_out, int out_size, void* d_ws, size_t ws_size,
                              hipStream_t stream) {
    const float* hs = (const float*)d_in[0];
    const float* Wq = (const float*)d_in[1];
    const float* bq = (const float*)d_in[2];
    const float* Wk = (const float*)d_in[3];
    const float* bk = (const float*)d_in[4];
    const float* Wv = (const float*)d_in[5];
    const float* bv = (const float*)d_in[6];
    float* out = (float*)d_out;

    char* ws = (char*)d_ws;
    u16* Qb = (u16*)(ws);                       // 4 MB  [16384][128] bf16 (pre-scaled)
    u16* Kb = (u16*)(ws + (size_t)(4  << 20));  // 4 MB
    u16* Vt = (u16*)(ws + (size_t)(8  << 20));  // 4 MB  [8][128][2048] (written by qkv epilogue)
    u16* Wp = (u16*)(ws + (size_t)(12 << 20));  // 1.5 MB [384][2048]

    hipLaunchKernelGGL(pack_weights, dim3(192), dim3(256), 0, stream, Wq, Wk, Wv, Wp);
    hipLaunchKernelGGL(qkv_gemm, dim3(256), dim3(512), 0, stream, hs, Wp, bq, bk, bv, Qb, Kb, Vt);
    hipLaunchKernelGGL(attn, dim3(1024), dim3(256), 0, stream, Qb, Kb, Vt, out);
}

// Round 17
// 124.922 us; speedup vs baseline: 1.0605x; 1.0605x over previous
//
#include <hip/hip_runtime.h>
#include <hip/hip_bf16.h>
#include <stdint.h>

#define B_DIM 8
#define S_LEN 2048
#define DMODEL 2048
#define HDIM 128

typedef __attribute__((ext_vector_type(4))) float f32x4;
typedef __attribute__((ext_vector_type(8))) short bf16x8;
typedef __attribute__((ext_vector_type(4))) short bf16x4;
typedef __attribute__((ext_vector_type(4))) unsigned int u32x4;
typedef unsigned short u16;
typedef unsigned int u32;

__device__ __forceinline__ u16 f2bf(float f) {
    union { float f; u32 u; } v; v.f = f;
    u32 u = v.u;
    u32 r = (u + 0x7fffu + ((u >> 16) & 1u)) >> 16;
    return (u16)r;
}

__device__ __forceinline__ u32 pk2bf(float a, float b) {
    float2 f2; f2.x = a; f2.y = b;
    __hip_bfloat162 h = __float22bfloat162_rn(f2);
    union { __hip_bfloat162 h; u32 u; } cv; cv.h = h;
    return cv.u;
}

__device__ __forceinline__ void async_copy16(u16* lds, const u16* g) {
    __builtin_amdgcn_global_load_lds((const __attribute__((address_space(1))) u32*)g,
                                     (__attribute__((address_space(3))) u32*)lds,
                                     16, 0, 0);
}

// ---------------- pack weights: transpose [2048 k][128 h] fp32 x3 -> bf16 Wp[384 h][2048 k]
__global__ void pack_weights(const float* __restrict__ Wq, const float* __restrict__ Wk,
                             const float* __restrict__ Wv, u16* __restrict__ Wp) {
    __shared__ u16 tl[64 * 64];
    int t = threadIdx.x;
    int bx = blockIdx.x;                 // 3 w * 32 kt * 2 ht = 192
    int w = bx >> 6;
    int kt = (bx >> 1) & 31;
    int ht = bx & 1;
    int k0 = kt * 64, h0 = ht * 64;
    const float* W = (w == 0) ? Wq : ((w == 1) ? Wk : Wv);

    int kl = t >> 2, hc = t & 3;
    const float* src = W + (size_t)(k0 + kl) * HDIM + h0 + hc * 16;
#pragma unroll
    for (int half = 0; half < 2; half++) {
        bf16x8 p;
#pragma unroll
        for (int j = 0; j < 8; j++) p[j] = (short)f2bf(src[half * 8 + j]);
        int slot = hc * 2 + half;
        *(bf16x8*)((char*)tl + kl * 128 + ((slot ^ (kl & 7)) << 4)) = p;
    }
    __syncthreads();
    int hl = t >> 2, kc = t & 3;
    u16* dst = Wp + (size_t)(w * HDIM + h0 + hl) * DMODEL + k0 + kc * 16;
#pragma unroll
    for (int half = 0; half < 2; half++) {
        bf16x8 p;
#pragma unroll
        for (int j = 0; j < 8; j++) {
            int k = kc * 16 + half * 8 + j;
            p[j] = *(u16*)((char*)tl + k * 128 + (((hl >> 3) ^ (k & 7)) << 4) + (hl & 7) * 2);
        }
        *(bf16x8*)(dst + half * 8) = p;
    }
}

// ---------------- fused QKV projection GEMM: [16384,2048] @ [2048,384] (bf16 MFMA)
// Round-14 kernel (best total): r11 structure + per-block k-ring offset (L2 hotspot
// de-phasing). BM=64, BN=384, BK=64, grid 256, 8 waves. vmcnt(2) keeps the 2
// A-prefetch loads in flight across the barrier. V written transposed. FROZEN.
// Ledger: BK=32 bank-conflicts (r8); LDS-free 2x slower (r9); BN=192/2blk-CU null
// (r10); ring-3/4 deeper prefetch null-to-worse (r12/r13).
__launch_bounds__(512)
__global__ void qkv_gemm(const float* __restrict__ hs, const u16* __restrict__ Wp,
                         const float* __restrict__ bq, const float* __restrict__ bk,
                         const float* __restrict__ bv,
                         u16* __restrict__ Qb, u16* __restrict__ Kb, u16* __restrict__ Vt) {
    __shared__ u16 As[2][64 * 64];       // 2 x 8 KB, 16B-slot XOR swizzle
    __shared__ u16 Bs[2][384 * 64];      // 2 x 48 KB, swizzled

    int t = threadIdx.x;
    int wv = t >> 6, l = t & 63, lr = l & 15, lq = l >> 4;
    int wm = wv >> 2, wn = wv & 3;
    int m0 = blockIdx.x * 64;
    int ko = ((blockIdx.x >> 3) & 31) << 6;   // k-ring start: unique per block within an XCD

#define KW(X) (((X) + ko) & (DMODEL - 1))

    f32x4 acc[2][6] = {};

    int ar = t >> 3, aq = t & 7;         // A staging: row 0..63, 8-float chunk 0..7
    const float* gA = hs + (size_t)(m0 + ar) * DMODEL + aq * 8;

    f32x4 p0A, p1A, p0B, p1B;            // two A-prefetch register sets (depth 2)

#define STAGE_B(K0, BUF)                                                    \
    {                                                                       \
        _Pragma("unroll")                                                   \
        for (int i = 0; i < 6; i++) {                                       \
            int c = i * 512 + t;                                            \
            int n = c >> 3, s = c & 7;                                      \
            async_copy16(&Bs[BUF][c * 8],                                   \
                         Wp + (size_t)n * DMODEL + (K0) + ((s ^ (n & 7)) * 8)); \
        }                                                                   \
    }
#define WRITE_A(BUF, V0, V1)                                                \
    {                                                                       \
        u32x4 pk;                                                           \
        pk.x = pk2bf(V0[0], V0[1]); pk.y = pk2bf(V0[2], V0[3]);             \
        pk.z = pk2bf(V1[0], V1[1]); pk.w = pk2bf(V1[2], V1[3]);             \
        *(u32x4*)((char*)&As[BUF][0] + ar * 128 + ((aq ^ (ar & 7)) << 4)) = pk; \
    }
#define COMPUTE(CUR)                                                        \
    {                                                                       \
        _Pragma("unroll")                                                   \
        for (int kk = 0; kk < 2; kk++) {                                    \
            bf16x8 afr[2], bfr[6];                                          \
            int slot = kk * 4 + lq;                                         \
            _Pragma("unroll")                                               \
            for (int mi = 0; mi < 2; mi++) {                                \
                int row = wm * 32 + mi * 16 + lr;                           \
                afr[mi] = *(bf16x8*)((char*)&As[CUR][0] + row * 128 + ((slot ^ (row & 7)) << 4)); \
            }                                                               \
            _Pragma("unroll")                                               \
            for (int ni = 0; ni < 6; ni++) {                                \
                int row = wn * 96 + ni * 16 + lr;                           \
                bfr[ni] = *(bf16x8*)((char*)&Bs[CUR][0] + row * 128 + ((slot ^ (row & 7)) << 4)); \
            }                                                               \
            __builtin_amdgcn_s_setprio(1);                                  \
            _Pragma("unroll")                                               \
            for (int mi = 0; mi < 2; mi++)                                  \
                _Pragma("unroll")                                           \
                for (int ni = 0; ni < 6; ni++)                              \
                    acc[mi][ni] = __builtin_amdgcn_mfma_f32_16x16x32_bf16(afr[mi], bfr[ni], acc[mi][ni], 0, 0, 0); \
            __builtin_amdgcn_s_setprio(0);                                  \
        }                                                                   \
    }
#define SYNC_PIPE                                                           \
    asm volatile("s_waitcnt vmcnt(2) lgkmcnt(0)" ::: "memory");             \
    __builtin_amdgcn_sched_barrier(0);                                      \
    __builtin_amdgcn_s_barrier();                                           \
    __builtin_amdgcn_sched_barrier(0);

    // prologue: tile ko into buf0; prefetch A(ko+64)
    p0A = *(const f32x4*)(gA + KW(0)); p1A = *(const f32x4*)(gA + KW(0) + 4);
    STAGE_B(KW(0), 0);
    WRITE_A(0, p0A, p1A);
    p0A = *(const f32x4*)(gA + KW(64)); p1A = *(const f32x4*)(gA + KW(64) + 4);
    __syncthreads();                     // full drain once (prologue only)

    for (int k0 = 0; k0 < DMODEL; k0 += 128) {
        // even step: compute buf0; stage tile(i+1)->buf1; prefetch A(i+2)
        {
            int ks = KW(k0 + 64);
            int kp = KW(k0 + 128);
            STAGE_B(ks, 1);
            p0B = *(const f32x4*)(gA + kp); p1B = *(const f32x4*)(gA + kp + 4);
            COMPUTE(0);
            WRITE_A(1, p0A, p1A);
            SYNC_PIPE
        }
        // odd step: compute buf1; stage->buf0; prefetch
        {
            int ks = KW(k0 + 128);
            int kp = KW(k0 + 192);
            STAGE_B(ks, 0);
            p0A = *(const f32x4*)(gA + kp); p1A = *(const f32x4*)(gA + kp + 4);
            COMPUTE(1);
            WRITE_A(0, p0B, p1B);
            SYNC_PIPE
        }
    }

    // epilogue: bias; Q pre-scaled by 1/sqrt(128); V written transposed to Vt[b][h][s]
#pragma unroll
    for (int ni = 0; ni < 6; ni++) {
        int col = wn * 96 + ni * 16 + lr;
        int w = col >> 7, h = col & 127;
        const float* bp = (w == 0) ? bq : ((w == 1) ? bk : bv);
        float bias = bp[h];
#pragma unroll
        for (int mi = 0; mi < 2; mi++) {
            int row0 = m0 + wm * 32 + mi * 16 + lq * 4;
            if (w == 2) {
                int b = row0 >> 11, s0 = row0 & (S_LEN - 1);
                bf16x4 pv;
#pragma unroll
                for (int r = 0; r < 4; r++) pv[r] = (short)f2bf(acc[mi][ni][r] + bias);
                *(bf16x4*)(Vt + (size_t)(b * HDIM + h) * S_LEN + s0) = pv;
            } else {
                float scale = (w == 0) ? 0.08838834764831845f : 1.0f;
                u16* dst = (w == 0) ? Qb : Kb;
#pragma unroll
                for (int r = 0; r < 4; r++)
                    dst[(size_t)(row0 + r) * HDIM + h] = f2bf((acc[mi][ni][r] + bias) * scale);
            }
        }
    }
#undef STAGE_B
#undef WRITE_A
#undef COMPUTE
#undef SYNC_PIPE
#undef KW
}

// ---------------- causal flash attention: 4 waves per block split the KV range of ONE
// 16-row Q tile (kt = wv, wv+4, ...); no barriers in main loop; LDS merge at the end.
// launch_bounds(256,3) cap ~168 regs: (256,4) cap=128 SPILLS — confirmed twice
// (r4-6 fat kernel, r16 lean kernel: WRITE 8.2->15MB, occupancy unchanged). FINAL.
// BATCHED LOAD ISSUE (r17): K-loads in 2 halves of 8, V-loads in groups of 8 —
// waits per tile: QK 4->2, PV 16->2. Peak live ~114 regs < 168 cap (r4's spill was
// the 128 cap, not batching per se).
// Defer-max (T13, THR=8) + shuffle-free common path (r15).
__launch_bounds__(256, 3)
__global__ void attn(const u16* __restrict__ Qb, const u16* __restrict__ Kb,
                     const u16* __restrict__ Vt, float* __restrict__ out) {
    __shared__ char lds[33280];          // Om[4][16][128] f32 (32768) + ml[4][16][2] f32 (512)
    float* Om = (float*)lds;
    float* ml = (float*)(lds + 32768);

    int t = threadIdx.x;
    int wv = t >> 6, l = t & 63, lr = l & 15, lq = l >> 4;
    int bx = blockIdx.x;                 // 1024 = 8 b x 128 qt
    int b = bx & 7;                      // batch == XCD for KV L2 locality
    int qt = 127 - (bx >> 3);            // descending work order
    int qr0 = qt * 16;
    size_t qbase = (size_t)b * S_LEN;
    char* Pw = lds + wv * 8192;          // P tile aliases this wave's own Om region

    bf16x8 aqf[4];
#pragma unroll
    for (int kk = 0; kk < 4; kk++)
        aqf[kk] = *(const bf16x8*)(Qb + (qbase + qr0 + lr) * HDIM + kk * 32 + lq * 8);

    f32x4 o_acc[8] = {};
    float m_run[4], l_run[4];
#pragma unroll
    for (int r = 0; r < 4; r++) { m_run[r] = -1e38f; l_run[r] = 0.f; }

    int ktd = qt >> 2;                   // diagonal 64-wide tile index
    const u16* Kbase = Kb + qbase * HDIM;
    const u16* Vbase = Vt + (size_t)b * HDIM * S_LEN;

    for (int kt = wv; kt <= ktd; kt += 4) {
        int kv0 = kt * 64;

        // S = Q K^T : K fragments from L2, batched 8-wide (2 halves)
        f32x4 sa[4] = {};
#pragma unroll
        for (int kh = 0; kh < 2; kh++) {
            bf16x8 bk8[2][4];
#pragma unroll
            for (int kk2 = 0; kk2 < 2; kk2++) {
                int kk = kh * 2 + kk2;
#pragma unroll
                for (int n = 0; n < 4; n++)
                    bk8[kk2][n] = *(const bf16x8*)(Kbase + (size_t)(kv0 + n * 16 + lr) * HDIM + kk * 32 + lq * 8);
            }
            __builtin_amdgcn_s_setprio(1);
#pragma unroll
            for (int kk2 = 0; kk2 < 2; kk2++)
#pragma unroll
                for (int n = 0; n < 4; n++)
                    sa[n] = __builtin_amdgcn_mfma_f32_16x16x32_bf16(aqf[kh * 2 + kk2], bk8[kk2][n], sa[n], 0, 0, 0);
            __builtin_amdgcn_s_setprio(0);
        }

        if (kt == ktd) {                 // causal mask on the diagonal tile
#pragma unroll
            for (int n = 0; n < 4; n++) {
                int col = kv0 + n * 16 + lr;
#pragma unroll
                for (int r = 0; r < 4; r++) {
                    int row = qr0 + lq * 4 + r;
                    if (col > row) sa[n][r] = -1e30f;
                }
            }
        }

        // shuffle-free online softmax (16-lane groups own 4 q-rows each)
#pragma unroll
        for (int r = 0; r < 4; r++) {
            float pmx = fmaxf(fmaxf(sa[0][r], sa[1][r]), fmaxf(sa[2][r], sa[3][r]));
            if (__any(pmx > m_run[r] + 8.0f)) {      // rare, wave-uniform
                float mx = pmx;
#pragma unroll
                for (int off = 8; off >= 1; off >>= 1) mx = fmaxf(mx, __shfl_xor(mx, off, 64));
                float mnew = fmaxf(m_run[r], mx);
                float f = __expf(m_run[r] - mnew);
                l_run[r] *= f;                       // per-lane partial scales linearly
                m_run[r] = mnew;
#pragma unroll
                for (int n = 0; n < 8; n++) o_acc[n][r] *= f;
            }
            int prow = lq * 4 + r;
            char* pb = Pw + prow * 128;
#pragma unroll
            for (int n = 0; n < 4; n++) {
                float e = __expf(sa[n][r] - m_run[r]);
                l_run[r] += e;                       // per-lane partial, no shuffles
                int col = n * 16 + lr;
                *(u16*)(pb + (((col >> 3) ^ (prow & 7)) << 4) + (col & 7) * 2) = f2bf(e);
            }
        }

        // O += P V : V fragments from L2, batched 8-wide per kk
#pragma unroll
        for (int kk = 0; kk < 2; kk++) {
            int slot = kk * 4 + lq;
            bf16x8 pa = *(bf16x8*)(Pw + lr * 128 + ((slot ^ (lr & 7)) << 4));
            bf16x8 vb8[8];
#pragma unroll
            for (int n = 0; n < 8; n++)
                vb8[n] = *(const bf16x8*)(Vbase + (size_t)(n * 16 + lr) * S_LEN + kv0 + kk * 32 + lq * 8);
            __builtin_amdgcn_s_setprio(1);
#pragma unroll
            for (int n = 0; n < 8; n++)
                o_acc[n] = __builtin_amdgcn_mfma_f32_16x16x32_bf16(pa, vb8[n], o_acc[n], 0, 0, 0);
            __builtin_amdgcn_s_setprio(0);
        }
    }

    // fold the per-lane l partials into group sums (once, not per tile)
#pragma unroll
    for (int r = 0; r < 4; r++) {
#pragma unroll
        for (int off = 8; off >= 1; off >>= 1) l_run[r] += __shfl_xor(l_run[r], off, 64);
    }

    // write partials (Om[wv] overwrites this wave's P area only after its last P read)
    __builtin_amdgcn_sched_barrier(0);
#pragma unroll
    for (int n = 0; n < 8; n++)
#pragma unroll
        for (int r = 0; r < 4; r++)
            Om[wv * 2048 + (lq * 4 + r) * 128 + n * 16 + lr] = o_acc[n][r];
    if (lr == 0) {
#pragma unroll
        for (int r = 0; r < 4; r++) {
            ml[wv * 32 + (lq * 4 + r) * 2 + 0] = m_run[r];
            ml[wv * 32 + (lq * 4 + r) * 2 + 1] = l_run[r];
        }
    }
    __syncthreads();

    // merge the 4 partials: thread -> (row = t>>4, cols (t&15)*8 .. +8)
    {
        int row = t >> 4, c0 = (t & 15) * 8;
        float m4[4], l4[4];
#pragma unroll
        for (int w = 0; w < 4; w++) {
            m4[w] = ml[w * 32 + row * 2 + 0];
            l4[w] = ml[w * 32 + row * 2 + 1];
        }
        float ms = fmaxf(fmaxf(m4[0], m4[1]), fmaxf(m4[2], m4[3]));
        float wt[4], ls = 0.f;
#pragma unroll
        for (int w = 0; w < 4; w++) { wt[w] = __expf(m4[w] - ms); ls += l4[w] * wt[w]; }
        float inv = 1.0f / ls;
        f32x4 r0 = (f32x4)0.f, r1 = (f32x4)0.f;
#pragma unroll
        for (int w = 0; w < 4; w++) {
            const f32x4* Op = (const f32x4*)(Om + w * 2048 + row * 128 + c0);
            r0 += Op[0] * wt[w];
            r1 += Op[1] * wt[w];
        }
        f32x4* dst = (f32x4*)(out + (qbase + qr0 + row) * HDIM + c0);
        dst[0] = r0 * inv;
        dst[1] = r1 * inv;
    }
}

extern "C" void kernel_launch(void* const* d_in, const int* in_sizes, int n_in,
                              void* d_out, int out_size, void* d_ws, size_t ws_size,
                              hipStream_t stream) {
    const float* hs = (const float*)d_in[0];
    const float* Wq = (const float*)d_in[1];
    const float* bq = (const float*)d_in[2];
    const float* Wk = (const float*)d_in[3];
    const float* bk = (const float*)d_in[4];
    const float* Wv = (const float*)d_in[5];
    const float* bv = (const float*)d_in[6];
    float* out = (float*)d_out;

    char* ws = (char*)d_ws;
    u16* Qb = (u16*)(ws);                       // 4 MB  [16384][128] bf16 (pre-scaled)
    u16* Kb = (u16*)(ws + (size_t)(4  << 20));  // 4 MB
    u16* Vt = (u16*)(ws + (size_t)(8  << 20));  // 4 MB  [8][128][2048] (written by qkv epilogue)
    u16* Wp = (u16*)(ws + (size_t)(12 << 20));  // 1.5 MB [384][2048]

    hipLaunchKernelGGL(pack_weights, dim3(192), dim3(256), 0, stream, Wq, Wk, Wv, Wp);
    hipLaunchKernelGGL(qkv_gemm, dim3(256), dim3(512), 0, stream, hs, Wp, bq, bk, bv, Qb, Kb, Vt);
    hipLaunchKernelGGL(attn, dim3(1024), dim3(256), 0, stream, Qb, Kb, Vt, out);
}

// Round 18
// 124.108 us; speedup vs baseline: 1.0675x; 1.0066x over previous
//
#include <hip/hip_runtime.h>
#include <hip/hip_bf16.h>
#include <stdint.h>

#define B_DIM 8
#define S_LEN 2048
#define DMODEL 2048
#define HDIM 128

typedef __attribute__((ext_vector_type(4))) float f32x4;
typedef __attribute__((ext_vector_type(8))) short bf16x8;
typedef __attribute__((ext_vector_type(4))) short bf16x4;
typedef __attribute__((ext_vector_type(4))) unsigned int u32x4;
typedef unsigned short u16;
typedef unsigned int u32;

__device__ __forceinline__ u16 f2bf(float f) {
    union { float f; u32 u; } v; v.f = f;
    u32 u = v.u;
    u32 r = (u + 0x7fffu + ((u >> 16) & 1u)) >> 16;
    return (u16)r;
}

__device__ __forceinline__ u32 pk2bf(float a, float b) {
    float2 f2; f2.x = a; f2.y = b;
    __hip_bfloat162 h = __float22bfloat162_rn(f2);
    union { __hip_bfloat162 h; u32 u; } cv; cv.h = h;
    return cv.u;
}

__device__ __forceinline__ void async_copy16(u16* lds, const u16* g) {
    __builtin_amdgcn_global_load_lds((const __attribute__((address_space(1))) u32*)g,
                                     (__attribute__((address_space(3))) u32*)lds,
                                     16, 0, 0);
}

// ---------------- pack weights: transpose [2048 k][128 h] fp32 x3 -> bf16 Wp[384 h][2048 k]
__global__ void pack_weights(const float* __restrict__ Wq, const float* __restrict__ Wk,
                             const float* __restrict__ Wv, u16* __restrict__ Wp) {
    __shared__ u16 tl[64 * 64];
    int t = threadIdx.x;
    int bx = blockIdx.x;                 // 3 w * 32 kt * 2 ht = 192
    int w = bx >> 6;
    int kt = (bx >> 1) & 31;
    int ht = bx & 1;
    int k0 = kt * 64, h0 = ht * 64;
    const float* W = (w == 0) ? Wq : ((w == 1) ? Wk : Wv);

    int kl = t >> 2, hc = t & 3;
    const float* src = W + (size_t)(k0 + kl) * HDIM + h0 + hc * 16;
#pragma unroll
    for (int half = 0; half < 2; half++) {
        bf16x8 p;
#pragma unroll
        for (int j = 0; j < 8; j++) p[j] = (short)f2bf(src[half * 8 + j]);
        int slot = hc * 2 + half;
        *(bf16x8*)((char*)tl + kl * 128 + ((slot ^ (kl & 7)) << 4)) = p;
    }
    __syncthreads();
    int hl = t >> 2, kc = t & 3;
    u16* dst = Wp + (size_t)(w * HDIM + h0 + hl) * DMODEL + k0 + kc * 16;
#pragma unroll
    for (int half = 0; half < 2; half++) {
        bf16x8 p;
#pragma unroll
        for (int j = 0; j < 8; j++) {
            int k = kc * 16 + half * 8 + j;
            p[j] = *(u16*)((char*)tl + k * 128 + (((hl >> 3) ^ (k & 7)) << 4) + (hl & 7) * 2);
        }
        *(bf16x8*)(dst + half * 8) = p;
    }
}

// ---------------- fused QKV projection GEMM: [16384,2048] @ [2048,384] (bf16 MFMA)
// Round-14 kernel (best total): r11 structure + per-block k-ring offset (L2 hotspot
// de-phasing). BM=64, BN=384, BK=64, grid 256, 8 waves. vmcnt(2) keeps the 2
// A-prefetch loads in flight across the barrier. V written transposed. FROZEN.
// Ledger: BK=32 bank-conflicts (r8); LDS-free 2x slower (r9); BN=192/2blk-CU null
// (r10); ring-3/4 deeper prefetch null-to-worse (r12/r13).
__launch_bounds__(512)
__global__ void qkv_gemm(const float* __restrict__ hs, const u16* __restrict__ Wp,
                         const float* __restrict__ bq, const float* __restrict__ bk,
                         const float* __restrict__ bv,
                         u16* __restrict__ Qb, u16* __restrict__ Kb, u16* __restrict__ Vt) {
    __shared__ u16 As[2][64 * 64];       // 2 x 8 KB, 16B-slot XOR swizzle
    __shared__ u16 Bs[2][384 * 64];      // 2 x 48 KB, swizzled

    int t = threadIdx.x;
    int wv = t >> 6, l = t & 63, lr = l & 15, lq = l >> 4;
    int wm = wv >> 2, wn = wv & 3;
    int m0 = blockIdx.x * 64;
    int ko = ((blockIdx.x >> 3) & 31) << 6;   // k-ring start: unique per block within an XCD

#define KW(X) (((X) + ko) & (DMODEL - 1))

    f32x4 acc[2][6] = {};

    int ar = t >> 3, aq = t & 7;         // A staging: row 0..63, 8-float chunk 0..7
    const float* gA = hs + (size_t)(m0 + ar) * DMODEL + aq * 8;

    f32x4 p0A, p1A, p0B, p1B;            // two A-prefetch register sets (depth 2)

#define STAGE_B(K0, BUF)                                                    \
    {                                                                       \
        _Pragma("unroll")                                                   \
        for (int i = 0; i < 6; i++) {                                       \
            int c = i * 512 + t;                                            \
            int n = c >> 3, s = c & 7;                                      \
            async_copy16(&Bs[BUF][c * 8],                                   \
                         Wp + (size_t)n * DMODEL + (K0) + ((s ^ (n & 7)) * 8)); \
        }                                                                   \
    }
#define WRITE_A(BUF, V0, V1)                                                \
    {                                                                       \
        u32x4 pk;                                                           \
        pk.x = pk2bf(V0[0], V0[1]); pk.y = pk2bf(V0[2], V0[3]);             \
        pk.z = pk2bf(V1[0], V1[1]); pk.w = pk2bf(V1[2], V1[3]);             \
        *(u32x4*)((char*)&As[BUF][0] + ar * 128 + ((aq ^ (ar & 7)) << 4)) = pk; \
    }
#define COMPUTE(CUR)                                                        \
    {                                                                       \
        _Pragma("unroll")                                                   \
        for (int kk = 0; kk < 2; kk++) {                                    \
            bf16x8 afr[2], bfr[6];                                          \
            int slot = kk * 4 + lq;                                         \
            _Pragma("unroll")                                               \
            for (int mi = 0; mi < 2; mi++) {                                \
                int row = wm * 32 + mi * 16 + lr;                           \
                afr[mi] = *(bf16x8*)((char*)&As[CUR][0] + row * 128 + ((slot ^ (row & 7)) << 4)); \
            }                                                               \
            _Pragma("unroll")                                               \
            for (int ni = 0; ni < 6; ni++) {                                \
                int row = wn * 96 + ni * 16 + lr;                           \
                bfr[ni] = *(bf16x8*)((char*)&Bs[CUR][0] + row * 128 + ((slot ^ (row & 7)) << 4)); \
            }                                                               \
            __builtin_amdgcn_s_setprio(1);                                  \
            _Pragma("unroll")                                               \
            for (int mi = 0; mi < 2; mi++)                                  \
                _Pragma("unroll")                                           \
                for (int ni = 0; ni < 6; ni++)                              \
                    acc[mi][ni] = __builtin_amdgcn_mfma_f32_16x16x32_bf16(afr[mi], bfr[ni], acc[mi][ni], 0, 0, 0); \
            __builtin_amdgcn_s_setprio(0);                                  \
        }                                                                   \
    }
#define SYNC_PIPE                                                           \
    asm volatile("s_waitcnt vmcnt(2) lgkmcnt(0)" ::: "memory");             \
    __builtin_amdgcn_sched_barrier(0);                                      \
    __builtin_amdgcn_s_barrier();                                           \
    __builtin_amdgcn_sched_barrier(0);

    // prologue: tile ko into buf0; prefetch A(ko+64)
    p0A = *(const f32x4*)(gA + KW(0)); p1A = *(const f32x4*)(gA + KW(0) + 4);
    STAGE_B(KW(0), 0);
    WRITE_A(0, p0A, p1A);
    p0A = *(const f32x4*)(gA + KW(64)); p1A = *(const f32x4*)(gA + KW(64) + 4);
    __syncthreads();                     // full drain once (prologue only)

    for (int k0 = 0; k0 < DMODEL; k0 += 128) {
        // even step: compute buf0; stage tile(i+1)->buf1; prefetch A(i+2)
        {
            int ks = KW(k0 + 64);
            int kp = KW(k0 + 128);
            STAGE_B(ks, 1);
            p0B = *(const f32x4*)(gA + kp); p1B = *(const f32x4*)(gA + kp + 4);
            COMPUTE(0);
            WRITE_A(1, p0A, p1A);
            SYNC_PIPE
        }
        // odd step: compute buf1; stage->buf0; prefetch
        {
            int ks = KW(k0 + 128);
            int kp = KW(k0 + 192);
            STAGE_B(ks, 0);
            p0A = *(const f32x4*)(gA + kp); p1A = *(const f32x4*)(gA + kp + 4);
            COMPUTE(1);
            WRITE_A(0, p0B, p1B);
            SYNC_PIPE
        }
    }

    // epilogue: bias; Q pre-scaled by 1/sqrt(128); V written transposed to Vt[b][h][s]
#pragma unroll
    for (int ni = 0; ni < 6; ni++) {
        int col = wn * 96 + ni * 16 + lr;
        int w = col >> 7, h = col & 127;
        const float* bp = (w == 0) ? bq : ((w == 1) ? bk : bv);
        float bias = bp[h];
#pragma unroll
        for (int mi = 0; mi < 2; mi++) {
            int row0 = m0 + wm * 32 + mi * 16 + lq * 4;
            if (w == 2) {
                int b = row0 >> 11, s0 = row0 & (S_LEN - 1);
                bf16x4 pv;
#pragma unroll
                for (int r = 0; r < 4; r++) pv[r] = (short)f2bf(acc[mi][ni][r] + bias);
                *(bf16x4*)(Vt + (size_t)(b * HDIM + h) * S_LEN + s0) = pv;
            } else {
                float scale = (w == 0) ? 0.08838834764831845f : 1.0f;
                u16* dst = (w == 0) ? Qb : Kb;
#pragma unroll
                for (int r = 0; r < 4; r++)
                    dst[(size_t)(row0 + r) * HDIM + h] = f2bf((acc[mi][ni][r] + bias) * scale);
            }
        }
    }
#undef STAGE_B
#undef WRITE_A
#undef COMPUTE
#undef SYNC_PIPE
#undef KW
}

// ---------------- causal flash attention: 4 waves per block split the KV range of ONE
// 16-row Q tile (kt == wv mod 4); no barriers in main loop; LDS merge at the end.
// launch_bounds(256,3): (256,4) cap=128 SPILLS — confirmed twice (r4-6, r16). FINAL.
// KV RING-START (r18, = r14's qkv fix applied to attn): all blocks of a batch used to
// start at kt=wv -> 32 same-XCD CUs request the SAME K/V lines in lockstep (L2 bank
// serialization). Per-block ring offset roff de-phases them; online softmax is
// order-independent, order fixed per block -> deterministic.
// Defer-max (T13, THR=8) + shuffle-free common path (r15). Per-n PV loads (r17
// batching was null; r15 form is the best-measured).
__launch_bounds__(256, 3)
__global__ void attn(const u16* __restrict__ Qb, const u16* __restrict__ Kb,
                     const u16* __restrict__ Vt, float* __restrict__ out) {
    __shared__ char lds[33280];          // Om[4][16][128] f32 (32768) + ml[4][16][2] f32 (512)
    float* Om = (float*)lds;
    float* ml = (float*)(lds + 32768);

    int t = threadIdx.x;
    int wv = t >> 6, l = t & 63, lr = l & 15, lq = l >> 4;
    int bx = blockIdx.x;                 // 1024 = 8 b x 128 qt
    int b = bx & 7;                      // batch == XCD for KV L2 locality
    int qt = 127 - (bx >> 3);            // descending work order
    int qr0 = qt * 16;
    size_t qbase = (size_t)b * S_LEN;
    char* Pw = lds + wv * 8192;          // P tile aliases this wave's own Om region

    bf16x8 aqf[4];
#pragma unroll
    for (int kk = 0; kk < 4; kk++)
        aqf[kk] = *(const bf16x8*)(Qb + (qbase + qr0 + lr) * HDIM + kk * 32 + lq * 8);

    f32x4 o_acc[8] = {};
    float m_run[4], l_run[4];
#pragma unroll
    for (int r = 0; r < 4; r++) { m_run[r] = -1e38f; l_run[r] = 0.f; }

    int ktd = qt >> 2;                   // diagonal 64-wide tile index
    const u16* Kbase = Kb + qbase * HDIM;
    const u16* Vbase = Vt + (size_t)b * HDIM * S_LEN;

    // this wave's tiles: kt = wv + 4*idx, idx in [0, cnt); start ring at roff
    int cnt = (ktd >= wv) ? (((ktd - wv) >> 2) + 1) : 0;
    int roff = (cnt > 0) ? ((bx >> 3) % cnt) : 0;

    for (int j = 0; j < cnt; ++j) {
        int idx = j + roff; if (idx >= cnt) idx -= cnt;
        int kt = wv + (idx << 2);
        int kv0 = kt * 64;

        // S = Q K^T : K fragments straight from global (L2-hit)
        f32x4 sa[4] = {};
#pragma unroll
        for (int kk = 0; kk < 4; kk++) {
            bf16x8 bk8[4];
#pragma unroll
            for (int n = 0; n < 4; n++)
                bk8[n] = *(const bf16x8*)(Kbase + (size_t)(kv0 + n * 16 + lr) * HDIM + kk * 32 + lq * 8);
            __builtin_amdgcn_s_setprio(1);
#pragma unroll
            for (int n = 0; n < 4; n++)
                sa[n] = __builtin_amdgcn_mfma_f32_16x16x32_bf16(aqf[kk], bk8[n], sa[n], 0, 0, 0);
            __builtin_amdgcn_s_setprio(0);
        }

        if (kt == ktd) {                 // causal mask on the diagonal tile
#pragma unroll
            for (int n = 0; n < 4; n++) {
                int col = kv0 + n * 16 + lr;
#pragma unroll
                for (int r = 0; r < 4; r++) {
                    int row = qr0 + lq * 4 + r;
                    if (col > row) sa[n][r] = -1e30f;
                }
            }
        }

        // shuffle-free online softmax (16-lane groups own 4 q-rows each)
#pragma unroll
        for (int r = 0; r < 4; r++) {
            float pmx = fmaxf(fmaxf(sa[0][r], sa[1][r]), fmaxf(sa[2][r], sa[3][r]));
            if (__any(pmx > m_run[r] + 8.0f)) {      // rare, wave-uniform
                float mx = pmx;
#pragma unroll
                for (int off = 8; off >= 1; off >>= 1) mx = fmaxf(mx, __shfl_xor(mx, off, 64));
                float mnew = fmaxf(m_run[r], mx);
                float f = __expf(m_run[r] - mnew);
                l_run[r] *= f;                       // per-lane partial scales linearly
                m_run[r] = mnew;
#pragma unroll
                for (int n = 0; n < 8; n++) o_acc[n][r] *= f;
            }
            int prow = lq * 4 + r;
            char* pb = Pw + prow * 128;
#pragma unroll
            for (int n = 0; n < 4; n++) {
                float e = __expf(sa[n][r] - m_run[r]);
                l_run[r] += e;                       // per-lane partial, no shuffles
                int col = n * 16 + lr;
                *(u16*)(pb + (((col >> 3) ^ (prow & 7)) << 4) + (col & 7) * 2) = f2bf(e);
            }
        }

        // O += P V : V fragments straight from global (L2-hit), per-n load+MFMA
        // (per-n form, NOT batched vb8[8]: spilled at (256,4) in r4; r17 batch null)
#pragma unroll
        for (int kk = 0; kk < 2; kk++) {
            int slot = kk * 4 + lq;
            bf16x8 pa = *(bf16x8*)(Pw + lr * 128 + ((slot ^ (lr & 7)) << 4));
            __builtin_amdgcn_s_setprio(1);
#pragma unroll
            for (int n = 0; n < 8; n++) {
                bf16x8 vb8 = *(const bf16x8*)(Vbase + (size_t)(n * 16 + lr) * S_LEN + kv0 + kk * 32 + lq * 8);
                o_acc[n] = __builtin_amdgcn_mfma_f32_16x16x32_bf16(pa, vb8, o_acc[n], 0, 0, 0);
            }
            __builtin_amdgcn_s_setprio(0);
        }
    }

    // fold the per-lane l partials into group sums (once, not per tile)
#pragma unroll
    for (int r = 0; r < 4; r++) {
#pragma unroll
        for (int off = 8; off >= 1; off >>= 1) l_run[r] += __shfl_xor(l_run[r], off, 64);
    }

    // write partials (Om[wv] overwrites this wave's P area only after its last P read)
    __builtin_amdgcn_sched_barrier(0);
#pragma unroll
    for (int n = 0; n < 8; n++)
#pragma unroll
        for (int r = 0; r < 4; r++)
            Om[wv * 2048 + (lq * 4 + r) * 128 + n * 16 + lr] = o_acc[n][r];
    if (lr == 0) {
#pragma unroll
        for (int r = 0; r < 4; r++) {
            ml[wv * 32 + (lq * 4 + r) * 2 + 0] = m_run[r];
            ml[wv * 32 + (lq * 4 + r) * 2 + 1] = l_run[r];
        }
    }
    __syncthreads();

    // merge the 4 partials: thread -> (row = t>>4, cols (t&15)*8 .. +8)
    {
        int row = t >> 4, c0 = (t & 15) * 8;
        float m4[4], l4[4];
#pragma unroll
        for (int w = 0; w < 4; w++) {
            m4[w] = ml[w * 32 + row * 2 + 0];
            l4[w] = ml[w * 32 + row * 2 + 1];
        }
        float ms = fmaxf(fmaxf(m4[0], m4[1]), fmaxf(m4[2], m4[3]));
        float wt[4], ls = 0.f;
#pragma unroll
        for (int w = 0; w < 4; w++) { wt[w] = __expf(m4[w] - ms); ls += l4[w] * wt[w]; }
        float inv = 1.0f / ls;
        f32x4 r0 = (f32x4)0.f, r1 = (f32x4)0.f;
#pragma unroll
        for (int w = 0; w < 4; w++) {
            const f32x4* Op = (const f32x4*)(Om + w * 2048 + row * 128 + c0);
            r0 += Op[0] * wt[w];
            r1 += Op[1] * wt[w];
        }
        f32x4* dst = (f32x4*)(out + (qbase + qr0 + row) * HDIM + c0);
        dst[0] = r0 * inv;
        dst[1] = r1 * inv;
    }
}

extern "C" void kernel_launch(void* const* d_in, const int* in_sizes, int n_in,
                              void* d_out, int out_size, void* d_ws, size_t ws_size,
                              hipStream_t stream) {
    const float* hs = (const float*)d_in[0];
    const float* Wq = (const float*)d_in[1];
    const float* bq = (const float*)d_in[2];
    const float* Wk = (const float*)d_in[3];
    const float* bk = (const float*)d_in[4];
    const float* Wv = (const float*)d_in[5];
    const float* bv = (const float*)d_in[6];
    float* out = (float*)d_out;

    char* ws = (char*)d_ws;
    u16* Qb = (u16*)(ws);                       // 4 MB  [16384][128] bf16 (pre-scaled)
    u16* Kb = (u16*)(ws + (size_t)(4  << 20));  // 4 MB
    u16* Vt = (u16*)(ws + (size_t)(8  << 20));  // 4 MB  [8][128][2048] (written by qkv epilogue)
    u16* Wp = (u16*)(ws + (size_t)(12 << 20));  // 1.5 MB [384][2048]

    hipLaunchKernelGGL(pack_weights, dim3(192), dim3(256), 0, stream, Wq, Wk, Wv, Wp);
    hipLaunchKernelGGL(qkv_gemm, dim3(256), dim3(512), 0, stream, hs, Wp, bq, bk, bv, Qb, Kb, Vt);
    hipLaunchKernelGGL(attn, dim3(1024), dim3(256), 0, stream, Qb, Kb, Vt, out);
}

// Round 19
// 108.162 us; speedup vs baseline: 1.2249x; 1.1474x over previous
//
#include <hip/hip_runtime.h>
#include <hip/hip_bf16.h>
#include <stdint.h>

#define B_DIM 8
#define S_LEN 2048
#define DMODEL 2048
#define HDIM 128

typedef __attribute__((ext_vector_type(4))) float f32x4;
typedef __attribute__((ext_vector_type(8))) short bf16x8;
typedef __attribute__((ext_vector_type(4))) short bf16x4;
typedef __attribute__((ext_vector_type(4))) unsigned int u32x4;
typedef unsigned short u16;
typedef unsigned int u32;

__device__ __forceinline__ u16 f2bf(float f) {
    union { float f; u32 u; } v; v.f = f;
    u32 u = v.u;
    u32 r = (u + 0x7fffu + ((u >> 16) & 1u)) >> 16;
    return (u16)r;
}

__device__ __forceinline__ u32 pk2bf(float a, float b) {
    float2 f2; f2.x = a; f2.y = b;
    __hip_bfloat162 h = __float22bfloat162_rn(f2);
    union { __hip_bfloat162 h; u32 u; } cv; cv.h = h;
    return cv.u;
}

__device__ __forceinline__ void async_copy16(u16* lds, const u16* g) {
    __builtin_amdgcn_global_load_lds((const __attribute__((address_space(1))) u32*)g,
                                     (__attribute__((address_space(3))) u32*)lds,
                                     16, 0, 0);
}

// ---------------- pack weights: transpose [2048 k][128 h] fp32 x3 -> bf16 Wp[384 h][2048 k]
__global__ void pack_weights(const float* __restrict__ Wq, const float* __restrict__ Wk,
                             const float* __restrict__ Wv, u16* __restrict__ Wp) {
    __shared__ u16 tl[64 * 64];
    int t = threadIdx.x;
    int bx = blockIdx.x;                 // 3 w * 32 kt * 2 ht = 192
    int w = bx >> 6;
    int kt = (bx >> 1) & 31;
    int ht = bx & 1;
    int k0 = kt * 64, h0 = ht * 64;
    const float* W = (w == 0) ? Wq : ((w == 1) ? Wk : Wv);

    int kl = t >> 2, hc = t & 3;
    const float* src = W + (size_t)(k0 + kl) * HDIM + h0 + hc * 16;
#pragma unroll
    for (int half = 0; half < 2; half++) {
        bf16x8 p;
#pragma unroll
        for (int j = 0; j < 8; j++) p[j] = (short)f2bf(src[half * 8 + j]);
        int slot = hc * 2 + half;
        *(bf16x8*)((char*)tl + kl * 128 + ((slot ^ (kl & 7)) << 4)) = p;
    }
    __syncthreads();
    int hl = t >> 2, kc = t & 3;
    u16* dst = Wp + (size_t)(w * HDIM + h0 + hl) * DMODEL + k0 + kc * 16;
#pragma unroll
    for (int half = 0; half < 2; half++) {
        bf16x8 p;
#pragma unroll
        for (int j = 0; j < 8; j++) {
            int k = kc * 16 + half * 8 + j;
            p[j] = *(u16*)((char*)tl + k * 128 + (((hl >> 3) ^ (k & 7)) << 4) + (hl & 7) * 2);
        }
        *(bf16x8*)(dst + half * 8) = p;
    }
}

// ---------------- fused QKV projection GEMM: [16384,2048] @ [2048,384] (bf16 MFMA)
// Round-14 kernel (best total): r11 structure + per-block k-ring offset (L2 hotspot
// de-phasing). BM=64, BN=384, BK=64, grid 256, 8 waves. vmcnt(2) keeps the 2
// A-prefetch loads in flight across the barrier. V written transposed. FROZEN.
// Ledger: BK=32 bank-conflicts (r8); LDS-free 2x slower (r9); BN=192/2blk-CU null
// (r10); ring-3/4 deeper prefetch null-to-worse (r12/r13).
__launch_bounds__(512)
__global__ void qkv_gemm(const float* __restrict__ hs, const u16* __restrict__ Wp,
                         const float* __restrict__ bq, const float* __restrict__ bk,
                         const float* __restrict__ bv,
                         u16* __restrict__ Qb, u16* __restrict__ Kb, u16* __restrict__ Vt) {
    __shared__ u16 As[2][64 * 64];       // 2 x 8 KB, 16B-slot XOR swizzle
    __shared__ u16 Bs[2][384 * 64];      // 2 x 48 KB, swizzled

    int t = threadIdx.x;
    int wv = t >> 6, l = t & 63, lr = l & 15, lq = l >> 4;
    int wm = wv >> 2, wn = wv & 3;
    int m0 = blockIdx.x * 64;
    int ko = ((blockIdx.x >> 3) & 31) << 6;   // k-ring start: unique per block within an XCD

#define KW(X) (((X) + ko) & (DMODEL - 1))

    f32x4 acc[2][6] = {};

    int ar = t >> 3, aq = t & 7;         // A staging: row 0..63, 8-float chunk 0..7
    const float* gA = hs + (size_t)(m0 + ar) * DMODEL + aq * 8;

    f32x4 p0A, p1A, p0B, p1B;            // two A-prefetch register sets (depth 2)

#define STAGE_B(K0, BUF)                                                    \
    {                                                                       \
        _Pragma("unroll")                                                   \
        for (int i = 0; i < 6; i++) {                                       \
            int c = i * 512 + t;                                            \
            int n = c >> 3, s = c & 7;                                      \
            async_copy16(&Bs[BUF][c * 8],                                   \
                         Wp + (size_t)n * DMODEL + (K0) + ((s ^ (n & 7)) * 8)); \
        }                                                                   \
    }
#define WRITE_A(BUF, V0, V1)                                                \
    {                                                                       \
        u32x4 pk;                                                           \
        pk.x = pk2bf(V0[0], V0[1]); pk.y = pk2bf(V0[2], V0[3]);             \
        pk.z = pk2bf(V1[0], V1[1]); pk.w = pk2bf(V1[2], V1[3]);             \
        *(u32x4*)((char*)&As[BUF][0] + ar * 128 + ((aq ^ (ar & 7)) << 4)) = pk; \
    }
#define COMPUTE(CUR)                                                        \
    {                                                                       \
        _Pragma("unroll")                                                   \
        for (int kk = 0; kk < 2; kk++) {                                    \
            bf16x8 afr[2], bfr[6];                                          \
            int slot = kk * 4 + lq;                                         \
            _Pragma("unroll")                                               \
            for (int mi = 0; mi < 2; mi++) {                                \
                int row = wm * 32 + mi * 16 + lr;                           \
                afr[mi] = *(bf16x8*)((char*)&As[CUR][0] + row * 128 + ((slot ^ (row & 7)) << 4)); \
            }                                                               \
            _Pragma("unroll")                                               \
            for (int ni = 0; ni < 6; ni++) {                                \
                int row = wn * 96 + ni * 16 + lr;                           \
                bfr[ni] = *(bf16x8*)((char*)&Bs[CUR][0] + row * 128 + ((slot ^ (row & 7)) << 4)); \
            }                                                               \
            __builtin_amdgcn_s_setprio(1);                                  \
            _Pragma("unroll")                                               \
            for (int mi = 0; mi < 2; mi++)                                  \
                _Pragma("unroll")                                           \
                for (int ni = 0; ni < 6; ni++)                              \
                    acc[mi][ni] = __builtin_amdgcn_mfma_f32_16x16x32_bf16(afr[mi], bfr[ni], acc[mi][ni], 0, 0, 0); \
            __builtin_amdgcn_s_setprio(0);                                  \
        }                                                                   \
    }
#define SYNC_PIPE                                                           \
    asm volatile("s_waitcnt vmcnt(2) lgkmcnt(0)" ::: "memory");             \
    __builtin_amdgcn_sched_barrier(0);                                      \
    __builtin_amdgcn_s_barrier();                                           \
    __builtin_amdgcn_sched_barrier(0);

    // prologue: tile ko into buf0; prefetch A(ko+64)
    p0A = *(const f32x4*)(gA + KW(0)); p1A = *(const f32x4*)(gA + KW(0) + 4);
    STAGE_B(KW(0), 0);
    WRITE_A(0, p0A, p1A);
    p0A = *(const f32x4*)(gA + KW(64)); p1A = *(const f32x4*)(gA + KW(64) + 4);
    __syncthreads();                     // full drain once (prologue only)

    for (int k0 = 0; k0 < DMODEL; k0 += 128) {
        // even step: compute buf0; stage tile(i+1)->buf1; prefetch A(i+2)
        {
            int ks = KW(k0 + 64);
            int kp = KW(k0 + 128);
            STAGE_B(ks, 1);
            p0B = *(const f32x4*)(gA + kp); p1B = *(const f32x4*)(gA + kp + 4);
            COMPUTE(0);
            WRITE_A(1, p0A, p1A);
            SYNC_PIPE
        }
        // odd step: compute buf1; stage->buf0; prefetch
        {
            int ks = KW(k0 + 128);
            int kp = KW(k0 + 192);
            STAGE_B(ks, 0);
            p0A = *(const f32x4*)(gA + kp); p1A = *(const f32x4*)(gA + kp + 4);
            COMPUTE(1);
            WRITE_A(0, p0B, p1B);
            SYNC_PIPE
        }
    }

    // epilogue: bias; Q pre-scaled by 1/sqrt(128); V written transposed to Vt[b][h][s]
#pragma unroll
    for (int ni = 0; ni < 6; ni++) {
        int col = wn * 96 + ni * 16 + lr;
        int w = col >> 7, h = col & 127;
        const float* bp = (w == 0) ? bq : ((w == 1) ? bk : bv);
        float bias = bp[h];
#pragma unroll
        for (int mi = 0; mi < 2; mi++) {
            int row0 = m0 + wm * 32 + mi * 16 + lq * 4;
            if (w == 2) {
                int b = row0 >> 11, s0 = row0 & (S_LEN - 1);
                bf16x4 pv;
#pragma unroll
                for (int r = 0; r < 4; r++) pv[r] = (short)f2bf(acc[mi][ni][r] + bias);
                *(bf16x4*)(Vt + (size_t)(b * HDIM + h) * S_LEN + s0) = pv;
            } else {
                float scale = (w == 0) ? 0.08838834764831845f : 1.0f;
                u16* dst = (w == 0) ? Qb : Kb;
#pragma unroll
                for (int r = 0; r < 4; r++)
                    dst[(size_t)(row0 + r) * HDIM + h] = f2bf((acc[mi][ni][r] + bias) * scale);
            }
        }
    }
#undef STAGE_B
#undef WRITE_A
#undef COMPUTE
#undef SYNC_PIPE
#undef KW
}

// ---------------- causal flash attention, QBLK=32 per wave (r19).
// Makespan fix: attn's duration was the single heaviest block (qt=127: 32 tiles/wave
// x 2.3us = 74us dispatch). Wave now owns 32 q-rows (2 MFMA row-groups); block = 4
// waves KV-split over the SAME 32 rows; grid 512 (8 b x 64 qt). Heaviest wave: 8
// tiles. K/V fetched once per tile serves 2x rows -> L2 traffic halved. LDS 65KB
// (Om[4][32][128] + ml; P aliases Om) -> 2 blocks/CU. launch_bounds(256,2): ~190
// live regs < 256 cap. Tripwire: WRITE_SIZE >> 8.2MB = spill -> revert.
// Defer-max (T13, THR=8) + shuffle-free common path (r15).
__launch_bounds__(256, 2)
__global__ void attn(const u16* __restrict__ Qb, const u16* __restrict__ Kb,
                     const u16* __restrict__ Vt, float* __restrict__ out) {
    __shared__ char lds[66560];          // Om[4][32][128] f32 (65536) + ml[4][32][2] f32 (1024)
    float* Om = (float*)lds;
    float* ml = (float*)(lds + 65536);

    int t = threadIdx.x;
    int wv = t >> 6, l = t & 63, lr = l & 15, lq = l >> 4;
    int bx = blockIdx.x;                 // 512 = 8 b x 64 qt
    int b = bx & 7;                      // batch == XCD for KV L2 locality
    int qt = 63 - (bx >> 3);             // descending work order: heavy blocks first
    int qr0 = qt * 32;
    size_t qbase = (size_t)b * S_LEN;
    char* Pw = lds + wv * 16384;         // P tile (32x128B = 4KB) aliases wave's Om region

    bf16x8 aqf[2][4];
#pragma unroll
    for (int mi = 0; mi < 2; mi++)
#pragma unroll
        for (int kk = 0; kk < 4; kk++)
            aqf[mi][kk] = *(const bf16x8*)(Qb + (qbase + qr0 + mi * 16 + lr) * HDIM + kk * 32 + lq * 8);

    f32x4 o_acc[2][8] = {};
    float m_run[2][4], l_run[2][4];
#pragma unroll
    for (int mi = 0; mi < 2; mi++)
#pragma unroll
        for (int r = 0; r < 4; r++) { m_run[mi][r] = -1e38f; l_run[mi][r] = 0.f; }

    int ktd = qt >> 1;                   // diagonal 64-wide tile index
    const u16* Kbase = Kb + qbase * HDIM;
    const u16* Vbase = Vt + (size_t)b * HDIM * S_LEN;

    int cnt = (ktd >= wv) ? (((ktd - wv) >> 2) + 1) : 0;

    for (int j = 0; j < cnt; ++j) {
        int kt = wv + (j << 2);
        int kv0 = kt * 64;

        // S = Q K^T for both 16-row groups; K loaded once per kk serves both
        f32x4 sa[2][4] = {};
#pragma unroll
        for (int kk = 0; kk < 4; kk++) {
            bf16x8 bk8[4];
#pragma unroll
            for (int n = 0; n < 4; n++)
                bk8[n] = *(const bf16x8*)(Kbase + (size_t)(kv0 + n * 16 + lr) * HDIM + kk * 32 + lq * 8);
            __builtin_amdgcn_s_setprio(1);
#pragma unroll
            for (int n = 0; n < 4; n++) {
                sa[0][n] = __builtin_amdgcn_mfma_f32_16x16x32_bf16(aqf[0][kk], bk8[n], sa[0][n], 0, 0, 0);
                sa[1][n] = __builtin_amdgcn_mfma_f32_16x16x32_bf16(aqf[1][kk], bk8[n], sa[1][n], 0, 0, 0);
            }
            __builtin_amdgcn_s_setprio(0);
        }

        if (kt == ktd) {                 // causal mask on the diagonal tile
#pragma unroll
            for (int n = 0; n < 4; n++) {
                int col = kv0 + n * 16 + lr;
#pragma unroll
                for (int mi = 0; mi < 2; mi++)
#pragma unroll
                    for (int r = 0; r < 4; r++) {
                        int row = qr0 + mi * 16 + lq * 4 + r;
                        if (col > row) sa[mi][n][r] = -1e30f;
                    }
            }
        }

        // shuffle-free online softmax (defer-max THR=8), both row groups
#pragma unroll
        for (int mi = 0; mi < 2; mi++) {
#pragma unroll
            for (int r = 0; r < 4; r++) {
                float pmx = fmaxf(fmaxf(sa[mi][0][r], sa[mi][1][r]), fmaxf(sa[mi][2][r], sa[mi][3][r]));
                if (__any(pmx > m_run[mi][r] + 8.0f)) {  // rare, wave-uniform
                    float mx = pmx;
#pragma unroll
                    for (int off = 8; off >= 1; off >>= 1) mx = fmaxf(mx, __shfl_xor(mx, off, 64));
                    float mnew = fmaxf(m_run[mi][r], mx);
                    float f = __expf(m_run[mi][r] - mnew);
                    l_run[mi][r] *= f;
                    m_run[mi][r] = mnew;
#pragma unroll
                    for (int n = 0; n < 8; n++) o_acc[mi][n][r] *= f;
                }
                int prow = mi * 16 + lq * 4 + r;
                char* pb = Pw + prow * 128;
#pragma unroll
                for (int n = 0; n < 4; n++) {
                    float e = __expf(sa[mi][n][r] - m_run[mi][r]);
                    l_run[mi][r] += e;               // per-lane partial, no shuffles
                    int col = n * 16 + lr;
                    *(u16*)(pb + (((col >> 3) ^ (prow & 7)) << 4) + (col & 7) * 2) = f2bf(e);
                }
            }
        }

        // O += P V : V loaded once per n serves both row groups
#pragma unroll
        for (int kk = 0; kk < 2; kk++) {
            int slot = kk * 4 + lq;
            int row0 = lr, row1 = 16 + lr;
            bf16x8 pa0 = *(bf16x8*)(Pw + row0 * 128 + ((slot ^ (row0 & 7)) << 4));
            bf16x8 pa1 = *(bf16x8*)(Pw + row1 * 128 + ((slot ^ (row1 & 7)) << 4));
            __builtin_amdgcn_s_setprio(1);
#pragma unroll
            for (int n = 0; n < 8; n++) {
                bf16x8 vb8 = *(const bf16x8*)(Vbase + (size_t)(n * 16 + lr) * S_LEN + kv0 + kk * 32 + lq * 8);
                o_acc[0][n] = __builtin_amdgcn_mfma_f32_16x16x32_bf16(pa0, vb8, o_acc[0][n], 0, 0, 0);
                o_acc[1][n] = __builtin_amdgcn_mfma_f32_16x16x32_bf16(pa1, vb8, o_acc[1][n], 0, 0, 0);
            }
            __builtin_amdgcn_s_setprio(0);
        }
    }

    // fold the per-lane l partials into group sums (once, not per tile)
#pragma unroll
    for (int mi = 0; mi < 2; mi++)
#pragma unroll
        for (int r = 0; r < 4; r++) {
#pragma unroll
            for (int off = 8; off >= 1; off >>= 1)
                l_run[mi][r] += __shfl_xor(l_run[mi][r], off, 64);
        }

    // write partials (Om[wv] overwrites this wave's P area only after its last P read)
    __builtin_amdgcn_sched_barrier(0);
#pragma unroll
    for (int mi = 0; mi < 2; mi++)
#pragma unroll
        for (int n = 0; n < 8; n++)
#pragma unroll
            for (int r = 0; r < 4; r++)
                Om[wv * 4096 + (mi * 16 + lq * 4 + r) * 128 + n * 16 + lr] = o_acc[mi][n][r];
    if (lr == 0) {
#pragma unroll
        for (int mi = 0; mi < 2; mi++)
#pragma unroll
            for (int r = 0; r < 4; r++) {
                int row = mi * 16 + lq * 4 + r;
                ml[wv * 64 + row * 2 + 0] = m_run[mi][r];
                ml[wv * 64 + row * 2 + 1] = l_run[mi][r];
            }
    }
    __syncthreads();

    // merge the 4 partials: thread -> (row = t>>3 in 0..31, cols (t&7)*16 .. +16)
    {
        int row = t >> 3, c0 = (t & 7) * 16;
        float m4[4], l4[4];
#pragma unroll
        for (int w = 0; w < 4; w++) {
            m4[w] = ml[w * 64 + row * 2 + 0];
            l4[w] = ml[w * 64 + row * 2 + 1];
        }
        float ms = fmaxf(fmaxf(m4[0], m4[1]), fmaxf(m4[2], m4[3]));
        float wt[4], ls = 0.f;
#pragma unroll
        for (int w = 0; w < 4; w++) { wt[w] = __expf(m4[w] - ms); ls += l4[w] * wt[w]; }
        float inv = 1.0f / ls;
        f32x4 r0 = (f32x4)0.f, r1 = (f32x4)0.f, r2 = (f32x4)0.f, r3 = (f32x4)0.f;
#pragma unroll
        for (int w = 0; w < 4; w++) {
            const f32x4* Op = (const f32x4*)(Om + w * 4096 + row * 128 + c0);
            r0 += Op[0] * wt[w];
            r1 += Op[1] * wt[w];
            r2 += Op[2] * wt[w];
            r3 += Op[3] * wt[w];
        }
        f32x4* dst = (f32x4*)(out + (qbase + qr0 + row) * HDIM + c0);
        dst[0] = r0 * inv;
        dst[1] = r1 * inv;
        dst[2] = r2 * inv;
        dst[3] = r3 * inv;
    }
}

extern "C" void kernel_launch(void* const* d_in, const int* in_sizes, int n_in,
                              void* d_out, int out_size, void* d_ws, size_t ws_size,
                              hipStream_t stream) {
    const float* hs = (const float*)d_in[0];
    const float* Wq = (const float*)d_in[1];
    const float* bq = (const float*)d_in[2];
    const float* Wk = (const float*)d_in[3];
    const float* bk = (const float*)d_in[4];
    const float* Wv = (const float*)d_in[5];
    const float* bv = (const float*)d_in[6];
    float* out = (float*)d_out;

    char* ws = (char*)d_ws;
    u16* Qb = (u16*)(ws);                       // 4 MB  [16384][128] bf16 (pre-scaled)
    u16* Kb = (u16*)(ws + (size_t)(4  << 20));  // 4 MB
    u16* Vt = (u16*)(ws + (size_t)(8  << 20));  // 4 MB  [8][128][2048] (written by qkv epilogue)
    u16* Wp = (u16*)(ws + (size_t)(12 << 20));  // 1.5 MB [384][2048]

    hipLaunchKernelGGL(pack_weights, dim3(192), dim3(256), 0, stream, Wq, Wk, Wv, Wp);
    hipLaunchKernelGGL(qkv_gemm, dim3(256), dim3(512), 0, stream, hs, Wp, bq, bk, bv, Qb, Kb, Vt);
    hipLaunchKernelGGL(attn, dim3(512), dim3(256), 0, stream, Qb, Kb, Vt, out);
}